// Round 6
// baseline (292.099 us; speedup 1.0000x reference)
//
#include <hip/hip_runtime.h>

#define BSZ 2
#define SEQ 2048
#define CH  1024
#define NH  16
#define HD  64
#define LOG2E 1.4426950408889634f
#define MASKC (-14426.950408889634f)   /* -10000 * log2(e) */

typedef short  bf16x8 __attribute__((ext_vector_type(8)));
typedef short  bf16x4 __attribute__((ext_vector_type(4)));
typedef float  f32x4  __attribute__((ext_vector_type(4)));

__device__ __forceinline__ short f2bf(float f) {
    union { float f; unsigned u; } v; v.f = f;
    unsigned r = v.u + 0x7FFFu + ((v.u >> 16) & 1u);   // RNE
    return (short)(r >> 16);
}
// round-half-up bf16 (1 ulp tie-only difference vs RNE, 2 VALU ops)
__device__ __forceinline__ short f2bf_fast(float f) {
    union { float f; unsigned u; } v; v.f = f;
    return (short)((v.u + 0x8000u) >> 16);
}
// Single-instruction exp2 THROUGH THE COMPILER (TRANS-op result hazard needs
// a compiler-inserted wait state; bare inline asm broke correctness in R6).
__device__ __forceinline__ float exp2_hw(float x) {
#if __has_builtin(__builtin_amdgcn_exp2f)
    return __builtin_amdgcn_exp2f(x);
#else
    float r;
    asm volatile("v_exp_f32 %0, %1\n\ts_nop 1" : "=v"(r) : "v"(x));
    return r;
#endif
}

// 16x16x16 bf16 MFMA (K=16): C/D layout of a 16x16 MFMA equals this op's
// B-operand layout, which is what makes register-resident P^T possible.
#if __has_builtin(__builtin_amdgcn_mfma_f32_16x16x16bf16_1k)
__device__ __forceinline__ f32x4 mfma16x16x16(bf16x4 a, bf16x4 b, f32x4 c) {
    return __builtin_amdgcn_mfma_f32_16x16x16bf16_1k(a, b, c, 0, 0, 0);
}
#else
__device__ __forceinline__ f32x4 mfma16x16x16(bf16x4 a, bf16x4 b, f32x4 c) {
    f32x4 d;
    asm("v_mfma_f32_16x16x16_bf16 %0, %1, %2, %3"
        : "=v"(d) : "v"(a), "v"(b), "v"(c));
    return d;
}
#endif

// ---------------------------------------------------------------------------
// PREP mega-kernel: one launch replaces 5 (cast Q, cast K, Wq^T, Wk^T, V^T).
//   blocks [0, 2048)        : query fp32 -> qc bf16
//   blocks [2048, 4096)     : key   fp32 -> kc bf16
//   blocks [4096, 4352)     : Wq [k][n] -> wtq [n][k] bf16
//   blocks [4352, 4608)     : Wk [k][n] -> wtk [n][k] bf16
//   blocks [4608, 5632)     : key [b][s][h*64+d] -> vtr [b*h][d][s] bf16
// ---------------------------------------------------------------------------
__global__ __launch_bounds__(256) void prep(
    const float* __restrict__ query, const float* __restrict__ key,
    const float* __restrict__ Wq, const float* __restrict__ Wk,
    short* __restrict__ qc, short* __restrict__ kc,
    short* __restrict__ wtq, short* __restrict__ wtk,
    short* __restrict__ vtr)
{
    __shared__ float tile[64][65];
    const int bid = blockIdx.x;
    const int tid = threadIdx.x;

    if (bid < 4096) {
        // ---- straight cast, 2048 elements per block ----
        const float* s = (bid < 2048) ? query : key;
        short*       d = (bid < 2048) ? qc : kc;
        long i = ((long)(bid & 2047) * 256 + tid) * 8;
        float4 v0 = *(const float4*)&s[i];
        float4 v1 = *(const float4*)&s[i + 4];
        bf16x8 o;
        o[0] = f2bf(v0.x); o[1] = f2bf(v0.y); o[2] = f2bf(v0.z); o[3] = f2bf(v0.w);
        o[4] = f2bf(v1.x); o[5] = f2bf(v1.y); o[6] = f2bf(v1.z); o[7] = f2bf(v1.w);
        *(bf16x8*)&d[i] = o;
        return;
    }

    // ---- 64x64 tiled transpose + cast ----
    const float* s; short* d;
    int r0, c0, srs, drs;
    if (bid < 4608) {
        int t = bid - 4096;           // 0..511
        s   = (t < 256) ? Wq : Wk;
        d   = (t < 256) ? wtq : wtk;
        t  &= 255;
        r0  = (t >> 4) * 64;          // k
        c0  = (t & 15) * 64;          // n
        srs = CH; drs = CH;
    } else {
        int t = bid - 4608;           // 0..1023
        int z = t >> 5;               // b*16+h, 0..31
        int sy = t & 31;              // s tile, 0..31
        s   = key + (long)(z >> 4) * SEQ * CH + (long)(z & 15) * HD;
        d   = vtr + (long)z * HD * SEQ;
        r0  = sy * 64;                // s
        c0  = 0;                      // d
        srs = CH; drs = SEQ;
    }

    const int r  = tid >> 2;          // 0..63
    const int c4 = (tid & 3) << 4;    // 0,16,32,48
    #pragma unroll
    for (int i = 0; i < 16; i += 4) {
        float4 v = *(const float4*)&s[(long)(r0 + r) * srs + c0 + c4 + i];
        tile[r][c4 + i + 0] = v.x;
        tile[r][c4 + i + 1] = v.y;
        tile[r][c4 + i + 2] = v.z;
        tile[r][c4 + i + 3] = v.w;
    }
    __syncthreads();
    bf16x8 o0, o1;
    #pragma unroll
    for (int i = 0; i < 8; i++) o0[i] = f2bf(tile[c4 + i][r]);
    #pragma unroll
    for (int i = 0; i < 8; i++) o1[i] = f2bf(tile[c4 + 8 + i][r]);
    *(bf16x8*)&d[(long)(c0 + r) * drs + r0 + c4 + 0] = o0;
    *(bf16x8*)&d[(long)(c0 + r) * drs + r0 + c4 + 8] = o1;
}

// ---------------------------------------------------------------------------
// Fused Q+K projection GEMM, all-bf16 inputs.  1D grid, XCD-SWIZZLED (R4):
// blocks sharing an A-panel (same m-tile, 8 n-tiles) land on ONE XCD so the
// 256 KB panel is fetched into that XCD's L2 once (T1; dispatch round-robins
// wgid%8 across XCDs).
// Y = bf16((X * W + bias) * scale).  128x128 tile, BK=64 (16 iters), 4 waves
// of 4x4 16x16x32 MFMAs x 2 k-halves.  Double-buffered LDS, ONE barrier per
// iter; staging writes + global prefetch issue before compute.
// ---------------------------------------------------------------------------
__global__ __launch_bounds__(256, 2) void proj_mfma(
    const short* __restrict__ Xq, const short* __restrict__ Xk,
    const short* __restrict__ Wtq, const short* __restrict__ Wtk,
    const float* __restrict__ bq_, const float* __restrict__ bk_,
    short* __restrict__ Yq, short* __restrict__ Yk)
{
    __shared__ short At[2][128 * 72];
    __shared__ short Bt[2][128 * 72];

    // XCD swizzle: bid -> (pair = m,z group on fixed XCD; xtile = n-tile)
    const int bid  = blockIdx.x;           // 0..511
    const int g    = bid >> 3, xcd = bid & 7;
    const int pair = ((g >> 3) << 3) | xcd;   // 0..63 = y*2+z
    const int xt   = g & 7;                   // n-tile 0..7
    const int yy   = pair >> 1;               // m-tile 0..31
    const int zz   = pair & 1;                // operand set

    const short* X    = zz ? Xk  : Xq;
    const short* Wt   = zz ? Wtk : Wtq;
    const float* bias = zz ? bk_ : bq_;
    short*       Y    = zz ? Yk  : Yq;
    const float scale = zz ? 1.0f : (0.125f * LOG2E);  // fold 1/sqrt(D)*log2e into Q

    const int tid  = threadIdx.x;
    const int lane = tid & 63, w = tid >> 6;
    const int quad = lane >> 4, t16 = lane & 15;
    const int m0 = yy * 128, n0 = xt * 128;
    const int srow = tid >> 1;            // 0..127 staging row
    const int shalf = (tid & 1) * 32;     // 0 / 32 k-half (shorts)

    f32x4 acc[4][4];
    #pragma unroll
    for (int i = 0; i < 4; i++)
        #pragma unroll
        for (int j = 0; j < 4; j++)
            acc[i][j] = (f32x4){0.f, 0.f, 0.f, 0.f};

    const int M0 = (w >> 1) * 64, N0 = (w & 1) * 64;
    const int NIT = CH / 64;

    bf16x8 ar[4], br[4];
    // tile 0 -> regs -> buf0; tile 1 -> regs
    #pragma unroll
    for (int c = 0; c < 4; c++) {
        ar[c] = *(const bf16x8*)&X [(long)(m0 + srow) * CH + shalf + 8 * c];
        br[c] = *(const bf16x8*)&Wt[(long)(n0 + srow) * CH + shalf + 8 * c];
    }
    #pragma unroll
    for (int c = 0; c < 4; c++) {
        *(bf16x8*)&At[0][srow * 72 + shalf + 8 * c] = ar[c];
        *(bf16x8*)&Bt[0][srow * 72 + shalf + 8 * c] = br[c];
    }
    #pragma unroll
    for (int c = 0; c < 4; c++) {
        ar[c] = *(const bf16x8*)&X [(long)(m0 + srow) * CH + 64 + shalf + 8 * c];
        br[c] = *(const bf16x8*)&Wt[(long)(n0 + srow) * CH + 64 + shalf + 8 * c];
    }
    __syncthreads();

    for (int it = 0; it < NIT; it++) {
        const int buf = it & 1;
        if (it + 1 < NIT) {
            #pragma unroll
            for (int c = 0; c < 4; c++) {
                *(bf16x8*)&At[buf ^ 1][srow * 72 + shalf + 8 * c] = ar[c];
                *(bf16x8*)&Bt[buf ^ 1][srow * 72 + shalf + 8 * c] = br[c];
            }
            if (it + 2 < NIT) {
                const long ko = (long)(it + 2) * 64;
                #pragma unroll
                for (int c = 0; c < 4; c++) {
                    ar[c] = *(const bf16x8*)&X [(long)(m0 + srow) * CH + ko + shalf + 8 * c];
                    br[c] = *(const bf16x8*)&Wt[(long)(n0 + srow) * CH + ko + shalf + 8 * c];
                }
            }
        }

        #pragma unroll
        for (int kk = 0; kk < 2; kk++) {
            bf16x8 af[4], bw[4];
            #pragma unroll
            for (int im = 0; im < 4; im++)
                af[im] = *(bf16x8*)&At[buf][(M0 + 16 * im + t16) * 72 + kk * 32 + quad * 8];
            #pragma unroll
            for (int jn = 0; jn < 4; jn++)
                bw[jn] = *(bf16x8*)&Bt[buf][(N0 + 16 * jn + t16) * 72 + kk * 32 + quad * 8];
            #pragma unroll
            for (int im = 0; im < 4; im++)
                #pragma unroll
                for (int jn = 0; jn < 4; jn++)
                    acc[im][jn] = __builtin_amdgcn_mfma_f32_16x16x32_bf16(
                        af[im], bw[jn], acc[im][jn], 0, 0, 0);
        }
        __syncthreads();
    }

    #pragma unroll
    for (int jn = 0; jn < 4; jn++) {
        float bs = bias[n0 + N0 + 16 * jn + t16];
        #pragma unroll
        for (int im = 0; im < 4; im++)
            #pragma unroll
            for (int reg = 0; reg < 4; reg++) {
                float y = (acc[im][jn][reg] + bs) * scale;
                Y[(long)(m0 + M0 + 16 * im + 4 * quad + reg) * (NH * HD)
                  + n0 + N0 + 16 * jn + t16] = f2bf(y);
            }
    }
}

// ---------------------------------------------------------------------------
// Flash attention, TRANSPOSED-SCORE form, register-resident P.
// R6: BARRIER-FREE / LDS-FREE main loop.
//   R5 post-mortem: FETCH fixed (69.7->12.4 MB) but time ~unchanged.  Cycle
//   accounting: MFMA ~25us + VALU ~22us + LDS ~19us SUMS to the measured
//   62us -> the per-iter barrier phase-locks all waves into the same pipe
//   at the same time (one pipe hot at a time).  Every prior null (R2 LDS/2,
//   R3 occupancy x2) preserved the phase-lock, hence invariance.
//   Fix: K/V tiles are L2-resident (R5) and the per-iter K-tile (8 KB) +
//   V-frags fit L1 -> read MFMA fragments DIRECTLY from global into regs.
//   No Kt/Vt LDS, no ds_write, no double-buffer, ZERO in-loop barriers.
//   Waves run free; MFMA/TRANS/VMEM overlap across the 8 waves/CU.
//   Latency cover: va loads issue at iter top (used ~500cy later after
//   QK+softmax); kb for it+1 issues after QK (used ~600cy later).  Register
//   double-buffer for kb via 2-unrolled loop with NAMED arrays (no runtime
//   indexing -> no scratch).  Msk stays in LDS (broadcast), one barrier
//   after init only.  XCD swizzle retained (FETCH win).  T5 setprio kept.
// ---------------------------------------------------------------------------
__global__ __launch_bounds__(256, 2) void attn_mfma(
    const short* __restrict__ qp,    // [B*S][1024] bf16, pre-scaled 0.125*log2e
    const short* __restrict__ kp,    // [B*S][1024] bf16
    const short* __restrict__ vt,    // [B*H][64][S] bf16 (V transposed)
    const int*   __restrict__ amask, // [B][S] 0/1
    float* __restrict__ out)         // [B][S][H][D] fp32
{
    __shared__ float Msk[SEQ];          // mask addend, whole row (8 KB)

    // XCD swizzle: bid -> (hb on fixed XCD, q-tile)
    const int bid = blockIdx.x;            // 0..511
    const int g   = bid >> 3, xcd = bid & 7;
    const int hb  = ((g >> 4) << 3) | xcd; // 0..31 = b*16+h, fixed XCD per hb
    const int qt  = g & 15;                // q-tile 0..15

    const int qt0 = qt * 128;
    const int h   = hb & 15;
    const int b   = hb >> 4;
    const int tid = threadIdx.x;
    const int lane = tid & 63, w = tid >> 6;
    const int quad = lane >> 4, t16 = lane & 15;

    // ---- mask row -> LDS float addend, once ----
    {
        int4 a0 = *(const int4*)&amask[b * SEQ + tid * 8];
        int4 a1 = *(const int4*)&amask[b * SEQ + tid * 8 + 4];
        float4 f0 = {a0.x ? 0.f : MASKC, a0.y ? 0.f : MASKC,
                     a0.z ? 0.f : MASKC, a0.w ? 0.f : MASKC};
        float4 f1 = {a1.x ? 0.f : MASKC, a1.y ? 0.f : MASKC,
                     a1.z ? 0.f : MASKC, a1.w ? 0.f : MASKC};
        *(float4*)&Msk[tid * 8]     = f0;
        *(float4*)&Msk[tid * 8 + 4] = f1;
    }

    // Q B-frags, loaded once: B[k = ds*32+quad*8+j][q = qm*16+t16]
    bf16x8 qf[2][2];
    #pragma unroll
    for (int qm = 0; qm < 2; qm++)
        #pragma unroll
        for (int ds = 0; ds < 2; ds++)
            qf[qm][ds] = *(const bf16x8*)&qp[
                (long)(b * SEQ + qt0 + w * 32 + qm * 16 + t16) * CH
                + h * HD + ds * 32 + quad * 8];

    f32x4 oa[4][2];                  // [dt][qm]: out^T [d=16dt+4quad+reg][q]
    float l_r[2];
    #pragma unroll
    for (int dt = 0; dt < 4; dt++)
        #pragma unroll
        for (int qm = 0; qm < 2; qm++)
            oa[dt][qm] = (f32x4){0.f, 0.f, 0.f, 0.f};
    l_r[0] = l_r[1] = 0.f;

    const long kbase = (long)(b * SEQ) * CH + h * HD;
    const long vbase = ((long)(b * NH + h) * HD) * SEQ;
    const int NIT = SEQ / 64;

    __syncthreads();   // Msk ready; ONLY barrier in the kernel body

    // K-fragment loader: kb[ds][jt] = A[m=key jt*16+t16][k=d ds*32+quad*8]
    auto loadKB = [&](bf16x8 (&kb)[2][4], int kt0) {
        #pragma unroll
        for (int ds = 0; ds < 2; ds++)
            #pragma unroll
            for (int jt = 0; jt < 4; jt++)
                kb[ds][jt] = *(const bf16x8*)&kp[
                    kbase + (long)(kt0 + jt * 16 + t16) * CH + ds * 32 + quad * 8];
    };

    bf16x8 kbA[2][4], kbB[2][4];
    loadKB(kbA, 0);

    // One k-iteration. kbC = this iter's K-frags (already in regs);
    // kbN = buffer to prefetch it+1's K-frags into.
    auto body = [&](bf16x8 (&kbC)[2][4], bf16x8 (&kbN)[2][4], int it) {
        const int kt0 = it * 64;

        // V-frags for THIS iter: issue first, consumed after QK+softmax.
        // va[dt][jt] = A[m=d dt*16+t16][k=key jt*16+quad*4]
        bf16x4 va[4][4];
        #pragma unroll
        for (int dt = 0; dt < 4; dt++)
            #pragma unroll
            for (int jt = 0; jt < 4; jt++)
                va[dt][jt] = *(const bf16x4*)&vt[
                    vbase + (long)(dt * 16 + t16) * SEQ + kt0 + jt * 16 + quad * 4];

        // mask addend (LDS broadcast)
        float4 mv4[4];
        #pragma unroll
        for (int jt = 0; jt < 4; jt++)
            mv4[jt] = *(const float4*)&Msk[kt0 + jt * 16 + quad * 4];

        // ---- S^T = K * Q^T (mask pre-loaded into the accumulator) ----
        f32x4 sa[2][4];
        #pragma unroll
        for (int qm = 0; qm < 2; qm++)
            #pragma unroll
            for (int jt = 0; jt < 4; jt++)
                sa[qm][jt] = (f32x4){mv4[jt].x, mv4[jt].y, mv4[jt].z, mv4[jt].w};
        #pragma unroll
        for (int ds = 0; ds < 2; ds++) {
            __builtin_amdgcn_s_setprio(1);
            #pragma unroll
            for (int qm = 0; qm < 2; qm++)
                #pragma unroll
                for (int jt = 0; jt < 4; jt++)
                    sa[qm][jt] = __builtin_amdgcn_mfma_f32_16x16x32_bf16(
                        kbC[ds][jt], qf[qm][ds], sa[qm][jt], 0, 0, 0);
            __builtin_amdgcn_s_setprio(0);
        }

        // prefetch next iter's K-frags (covered by softmax+PV below)
        if (it + 1 < NIT) loadKB(kbN, kt0 + 64);

        // ---- per-jt: softmax slice + PV MFMA (pb live range = 1 jt) ----
        #pragma unroll
        for (int jt = 0; jt < 4; jt++) {
            bf16x4 pbq[2];
            #pragma unroll
            for (int qm = 0; qm < 2; qm++) {
                float p0 = exp2_hw(sa[qm][jt][0]);
                float p1 = exp2_hw(sa[qm][jt][1]);
                float p2 = exp2_hw(sa[qm][jt][2]);
                float p3 = exp2_hw(sa[qm][jt][3]);
                l_r[qm] += (p0 + p1) + (p2 + p3);
                bf16x4 pk;
                pk[0] = f2bf_fast(p0); pk[1] = f2bf_fast(p1);
                pk[2] = f2bf_fast(p2); pk[3] = f2bf_fast(p3);
                pbq[qm] = pk;
            }
            __builtin_amdgcn_s_setprio(1);
            #pragma unroll
            for (int dt = 0; dt < 4; dt++)
                #pragma unroll
                for (int qm = 0; qm < 2; qm++)
                    oa[dt][qm] = mfma16x16x16(va[dt][jt], pbq[qm], oa[dt][qm]);
            __builtin_amdgcn_s_setprio(0);
        }
    };

    #pragma unroll 1
    for (int itp = 0; itp < NIT; itp += 2) {
        body(kbA, kbB, itp);
        body(kbB, kbA, itp + 1);
    }

    // ---- epilogue: quad-reduce l, normalize, store out^T -> out ----
    #pragma unroll
    for (int qm = 0; qm < 2; qm++) {
        float l = l_r[qm];
        l += __shfl_xor(l, 16, 64);
        l += __shfl_xor(l, 32, 64);
        float inv = 1.0f / l;
        int q = qt0 + w * 32 + qm * 16 + t16;
        #pragma unroll
        for (int dt = 0; dt < 4; dt++) {
            f32x4 o = oa[dt][qm];
            float4 st = {o[0] * inv, o[1] * inv, o[2] * inv, o[3] * inv};
            *(float4*)&out[((long)(b * SEQ + q) * NH + h) * HD + dt * 16 + quad * 4] = st;
        }
    }
}

extern "C" void kernel_launch(void* const* d_in, const int* in_sizes, int n_in,
                              void* d_out, int out_size, void* d_ws, size_t ws_size,
                              hipStream_t stream) {
    const float* query = (const float*)d_in[0];
    const float* key   = (const float*)d_in[1];
    const int*   amask = (const int*)d_in[2];
    const float* Wq    = (const float*)d_in[3];
    const float* bq    = (const float*)d_in[4];
    const float* Wk    = (const float*)d_in[5];
    const float* bk    = (const float*)d_in[6];
    float* out = (float*)d_out;

    char* ws = (char*)d_ws;
    const long MB = 1024 * 1024;
    short* qc  = (short*)(ws + 0 * MB);    // query bf16 [4096][1024] (8 MB)
    short* kc  = (short*)(ws + 8 * MB);    // key   bf16 [4096][1024] (8 MB)
    short* qp  = (short*)(ws + 16 * MB);   // Q proj bf16 (8 MB)
    short* kp  = (short*)(ws + 24 * MB);   // K proj bf16 (8 MB)
    short* vtr = (short*)(ws + 32 * MB);   // V^T bf16 [B*H][64][2048] (8 MB)
    short* wtq = (short*)(ws + 40 * MB);   // Wq^T bf16 (2 MB)
    short* wtk = (short*)(ws + 42 * MB);   // Wk^T bf16 (2 MB)

    prep<<<dim3(5632), 256, 0, stream>>>(query, key, Wq, Wk, qc, kc, wtq, wtk, vtr);

    proj_mfma<<<dim3(512), 256, 0, stream>>>(qc, kc, wtq, wtk, bq, bk, qp, kp);

    attn_mfma<<<dim3(512), 256, 0, stream>>>(qp, kp, vtr, amask, out);
}

// Round 7
// 247.058 us; speedup vs baseline: 1.1823x; 1.1823x over previous
//
#include <hip/hip_runtime.h>

#define BSZ 2
#define SEQ 2048
#define CH  1024
#define NH  16
#define HD  64
#define LOG2E 1.4426950408889634f
#define MASKC (-14426.950408889634f)   /* -10000 * log2(e) */

typedef short  bf16x8 __attribute__((ext_vector_type(8)));
typedef short  bf16x4 __attribute__((ext_vector_type(4)));
typedef float  f32x4  __attribute__((ext_vector_type(4)));

__device__ __forceinline__ short f2bf(float f) {
    union { float f; unsigned u; } v; v.f = f;
    unsigned r = v.u + 0x7FFFu + ((v.u >> 16) & 1u);   // RNE
    return (short)(r >> 16);
}
// Single-instruction exp2 THROUGH THE COMPILER (TRANS-op result hazard needs
// a compiler-inserted wait state; bare inline asm broke correctness earlier).
__device__ __forceinline__ float exp2_hw(float x) {
#if __has_builtin(__builtin_amdgcn_exp2f)
    return __builtin_amdgcn_exp2f(x);
#else
    float r;
    asm volatile("v_exp_f32 %0, %1\n\ts_nop 1" : "=v"(r) : "v"(x));
    return r;
#endif
}

// Pack 4 f32 -> bf16x4 via v_cvt_pk_bf16_f32 (RNE, 2 instrs instead of ~10
// VALU).  No builtin on gfx950 (learn_hip m240) -> inline asm.  s_nop 1
// guards the TRANS(v_exp)->asm-consumer hazard the compiler can't see into;
// early-clobber so outputs don't alias inputs.
__device__ __forceinline__ bf16x4 pack4_rne(float p0, float p1, float p2, float p3) {
    unsigned lo, hi;
    asm("s_nop 1\n\t"
        "v_cvt_pk_bf16_f32 %0, %2, %3\n\t"
        "v_cvt_pk_bf16_f32 %1, %4, %5"
        : "=&v"(lo), "=&v"(hi)
        : "v"(p0), "v"(p1), "v"(p2), "v"(p3));
    union { unsigned u[2]; bf16x4 v; } r;
    r.u[0] = lo; r.u[1] = hi;
    return r.v;
}

// 16x16x16 bf16 MFMA (K=16): C/D layout of a 16x16 MFMA equals this op's
// B-operand layout, which is what makes register-resident P^T possible.
#if __has_builtin(__builtin_amdgcn_mfma_f32_16x16x16bf16_1k)
__device__ __forceinline__ f32x4 mfma16x16x16(bf16x4 a, bf16x4 b, f32x4 c) {
    return __builtin_amdgcn_mfma_f32_16x16x16bf16_1k(a, b, c, 0, 0, 0);
}
#else
__device__ __forceinline__ f32x4 mfma16x16x16(bf16x4 a, bf16x4 b, f32x4 c) {
    f32x4 d;
    asm("v_mfma_f32_16x16x16_bf16 %0, %1, %2, %3"
        : "=v"(d) : "v"(a), "v"(b), "v"(c));
    return d;
}
#endif

// ---------------------------------------------------------------------------
// PREP mega-kernel: one launch replaces 5 (cast Q, cast K, Wq^T, Wk^T, V^T).
//   blocks [0, 2048)        : query fp32 -> qc bf16
//   blocks [2048, 4096)     : key   fp32 -> kc bf16
//   blocks [4096, 4352)     : Wq [k][n] -> wtq [n][k] bf16
//   blocks [4352, 4608)     : Wk [k][n] -> wtk [n][k] bf16
//   blocks [4608, 5632)     : key [b][s][h*64+d] -> vtr [b*h][d][s] bf16
// ---------------------------------------------------------------------------
__global__ __launch_bounds__(256) void prep(
    const float* __restrict__ query, const float* __restrict__ key,
    const float* __restrict__ Wq, const float* __restrict__ Wk,
    short* __restrict__ qc, short* __restrict__ kc,
    short* __restrict__ wtq, short* __restrict__ wtk,
    short* __restrict__ vtr)
{
    __shared__ float tile[64][65];
    const int bid = blockIdx.x;
    const int tid = threadIdx.x;

    if (bid < 4096) {
        // ---- straight cast, 2048 elements per block ----
        const float* s = (bid < 2048) ? query : key;
        short*       d = (bid < 2048) ? qc : kc;
        long i = ((long)(bid & 2047) * 256 + tid) * 8;
        float4 v0 = *(const float4*)&s[i];
        float4 v1 = *(const float4*)&s[i + 4];
        bf16x8 o;
        o[0] = f2bf(v0.x); o[1] = f2bf(v0.y); o[2] = f2bf(v0.z); o[3] = f2bf(v0.w);
        o[4] = f2bf(v1.x); o[5] = f2bf(v1.y); o[6] = f2bf(v1.z); o[7] = f2bf(v1.w);
        *(bf16x8*)&d[i] = o;
        return;
    }

    // ---- 64x64 tiled transpose + cast ----
    const float* s; short* d;
    int r0, c0, srs, drs;
    if (bid < 4608) {
        int t = bid - 4096;           // 0..511
        s   = (t < 256) ? Wq : Wk;
        d   = (t < 256) ? wtq : wtk;
        t  &= 255;
        r0  = (t >> 4) * 64;          // k
        c0  = (t & 15) * 64;          // n
        srs = CH; drs = CH;
    } else {
        int t = bid - 4608;           // 0..1023
        int z = t >> 5;               // b*16+h, 0..31
        int sy = t & 31;              // s tile, 0..31
        s   = key + (long)(z >> 4) * SEQ * CH + (long)(z & 15) * HD;
        d   = vtr + (long)z * HD * SEQ;
        r0  = sy * 64;                // s
        c0  = 0;                      // d
        srs = CH; drs = SEQ;
    }

    const int r  = tid >> 2;          // 0..63
    const int c4 = (tid & 3) << 4;    // 0,16,32,48
    #pragma unroll
    for (int i = 0; i < 16; i += 4) {
        float4 v = *(const float4*)&s[(long)(r0 + r) * srs + c0 + c4 + i];
        tile[r][c4 + i + 0] = v.x;
        tile[r][c4 + i + 1] = v.y;
        tile[r][c4 + i + 2] = v.z;
        tile[r][c4 + i + 3] = v.w;
    }
    __syncthreads();
    bf16x8 o0, o1;
    #pragma unroll
    for (int i = 0; i < 8; i++) o0[i] = f2bf(tile[c4 + i][r]);
    #pragma unroll
    for (int i = 0; i < 8; i++) o1[i] = f2bf(tile[c4 + 8 + i][r]);
    *(bf16x8*)&d[(long)(c0 + r) * drs + r0 + c4 + 0] = o0;
    *(bf16x8*)&d[(long)(c0 + r) * drs + r0 + c4 + 8] = o1;
}

// ---------------------------------------------------------------------------
// Fused Q+K projection GEMM, all-bf16 inputs.  1D grid, XCD-SWIZZLED (R4):
// blocks sharing an A-panel (same m-tile, 8 n-tiles) land on ONE XCD so the
// 256 KB panel is fetched into that XCD's L2 once.
// Y = bf16((X * W + bias) * scale).  128x128 tile, BK=64 (16 iters), 4 waves
// of 4x4 16x16x32 MFMAs x 2 k-halves.  Double-buffered LDS, ONE barrier per
// iter; staging writes + global prefetch issue before compute.
// ---------------------------------------------------------------------------
__global__ __launch_bounds__(256, 2) void proj_mfma(
    const short* __restrict__ Xq, const short* __restrict__ Xk,
    const short* __restrict__ Wtq, const short* __restrict__ Wtk,
    const float* __restrict__ bq_, const float* __restrict__ bk_,
    short* __restrict__ Yq, short* __restrict__ Yk)
{
    __shared__ short At[2][128 * 72];
    __shared__ short Bt[2][128 * 72];

    // XCD swizzle: bid -> (pair = m,z group on fixed XCD; xtile = n-tile)
    const int bid  = blockIdx.x;           // 0..511
    const int g    = bid >> 3, xcd = bid & 7;
    const int pair = ((g >> 3) << 3) | xcd;   // 0..63 = y*2+z
    const int xt   = g & 7;                   // n-tile 0..7
    const int yy   = pair >> 1;               // m-tile 0..31
    const int zz   = pair & 1;                // operand set

    const short* X    = zz ? Xk  : Xq;
    const short* Wt   = zz ? Wtk : Wtq;
    const float* bias = zz ? bk_ : bq_;
    short*       Y    = zz ? Yk  : Yq;
    const float scale = zz ? 1.0f : (0.125f * LOG2E);  // fold 1/sqrt(D)*log2e into Q

    const int tid  = threadIdx.x;
    const int lane = tid & 63, w = tid >> 6;
    const int quad = lane >> 4, t16 = lane & 15;
    const int m0 = yy * 128, n0 = xt * 128;
    const int srow = tid >> 1;            // 0..127 staging row
    const int shalf = (tid & 1) * 32;     // 0 / 32 k-half (shorts)

    f32x4 acc[4][4];
    #pragma unroll
    for (int i = 0; i < 4; i++)
        #pragma unroll
        for (int j = 0; j < 4; j++)
            acc[i][j] = (f32x4){0.f, 0.f, 0.f, 0.f};

    const int M0 = (w >> 1) * 64, N0 = (w & 1) * 64;
    const int NIT = CH / 64;

    bf16x8 ar[4], br[4];
    // tile 0 -> regs -> buf0; tile 1 -> regs
    #pragma unroll
    for (int c = 0; c < 4; c++) {
        ar[c] = *(const bf16x8*)&X [(long)(m0 + srow) * CH + shalf + 8 * c];
        br[c] = *(const bf16x8*)&Wt[(long)(n0 + srow) * CH + shalf + 8 * c];
    }
    #pragma unroll
    for (int c = 0; c < 4; c++) {
        *(bf16x8*)&At[0][srow * 72 + shalf + 8 * c] = ar[c];
        *(bf16x8*)&Bt[0][srow * 72 + shalf + 8 * c] = br[c];
    }
    #pragma unroll
    for (int c = 0; c < 4; c++) {
        ar[c] = *(const bf16x8*)&X [(long)(m0 + srow) * CH + 64 + shalf + 8 * c];
        br[c] = *(const bf16x8*)&Wt[(long)(n0 + srow) * CH + 64 + shalf + 8 * c];
    }
    __syncthreads();

    for (int it = 0; it < NIT; it++) {
        const int buf = it & 1;
        if (it + 1 < NIT) {
            #pragma unroll
            for (int c = 0; c < 4; c++) {
                *(bf16x8*)&At[buf ^ 1][srow * 72 + shalf + 8 * c] = ar[c];
                *(bf16x8*)&Bt[buf ^ 1][srow * 72 + shalf + 8 * c] = br[c];
            }
            if (it + 2 < NIT) {
                const long ko = (long)(it + 2) * 64;
                #pragma unroll
                for (int c = 0; c < 4; c++) {
                    ar[c] = *(const bf16x8*)&X [(long)(m0 + srow) * CH + ko + shalf + 8 * c];
                    br[c] = *(const bf16x8*)&Wt[(long)(n0 + srow) * CH + ko + shalf + 8 * c];
                }
            }
        }

        #pragma unroll
        for (int kk = 0; kk < 2; kk++) {
            bf16x8 af[4], bw[4];
            #pragma unroll
            for (int im = 0; im < 4; im++)
                af[im] = *(bf16x8*)&At[buf][(M0 + 16 * im + t16) * 72 + kk * 32 + quad * 8];
            #pragma unroll
            for (int jn = 0; jn < 4; jn++)
                bw[jn] = *(bf16x8*)&Bt[buf][(N0 + 16 * jn + t16) * 72 + kk * 32 + quad * 8];
            #pragma unroll
            for (int im = 0; im < 4; im++)
                #pragma unroll
                for (int jn = 0; jn < 4; jn++)
                    acc[im][jn] = __builtin_amdgcn_mfma_f32_16x16x32_bf16(
                        af[im], bw[jn], acc[im][jn], 0, 0, 0);
        }
        __syncthreads();
    }

    #pragma unroll
    for (int jn = 0; jn < 4; jn++) {
        float bs = bias[n0 + N0 + 16 * jn + t16];
        #pragma unroll
        for (int im = 0; im < 4; im++)
            #pragma unroll
            for (int reg = 0; reg < 4; reg++) {
                float y = (acc[im][jn][reg] + bs) * scale;
                Y[(long)(m0 + M0 + 16 * im + 4 * quad + reg) * (NH * HD)
                  + n0 + N0 + 16 * jn + t16] = f2bf(y);
            }
    }
}

// ---------------------------------------------------------------------------
// Flash attention, TRANSPOSED-SCORE form, register-resident P.
// R7 = R5 base (best verified: 62 µs) minus the V-LDS term, plus cvt_pk.
//   R6 post-mortem: removing K+V LDS AND barriers needed ~160 live VGPRs;
//   compiler allocated 104 and SANK the loads -> pure load-use serialization
//   (11%/11% util, 3x slower).  LDS staging = decoupling, not just BW.
//   R7 keeps K LDS-staged + per-iter barrier (decoupled), but reads V
//   fragments DIRECTLY from global (vtr is L2-resident per R5's FETCH data;
//   L1 serves the 8 KB tile after the first wave).  va[4][4] = +32 VGPR
//   (~100 total, under the 128 cap -> no sinking).  Issued at iter top,
//   consumed after staging+mask+QK+softmax (~400 cy cover).
//   Removes 8 KB/w/iter LDS reads + 2 KB/w/iter writes (~half the LDS term
//   in the sum-of-pipes model).  cvt_pk packing cuts ~100 VALU cyc/iter.
//   XCD swizzle, LDS mask, setprio retained.
// ---------------------------------------------------------------------------
__global__ __launch_bounds__(256, 2) void attn_mfma(
    const short* __restrict__ qp,    // [B*S][1024] bf16, pre-scaled 0.125*log2e
    const short* __restrict__ kp,    // [B*S][1024] bf16
    const short* __restrict__ vt,    // [B*H][64][S] bf16 (V transposed)
    const int*   __restrict__ amask, // [B][S] 0/1
    float* __restrict__ out)         // [B][S][H][D] fp32
{
    __shared__ short Kt[2][64 * 72];    // [key][d]
    __shared__ float Msk[SEQ];          // mask addend, whole row (8 KB)

    // XCD swizzle: bid -> (hb on fixed XCD, q-tile)
    const int bid = blockIdx.x;            // 0..511
    const int g   = bid >> 3, xcd = bid & 7;
    const int hb  = ((g >> 4) << 3) | xcd; // 0..31 = b*16+h, fixed XCD per hb
    const int qt  = g & 15;                // q-tile 0..15

    const int qt0 = qt * 128;
    const int h   = hb & 15;
    const int b   = hb >> 4;
    const int tid = threadIdx.x;
    const int lane = tid & 63, w = tid >> 6;
    const int quad = lane >> 4, t16 = lane & 15;

    // ---- mask row -> LDS float addend, once ----
    {
        int4 a0 = *(const int4*)&amask[b * SEQ + tid * 8];
        int4 a1 = *(const int4*)&amask[b * SEQ + tid * 8 + 4];
        float4 f0 = {a0.x ? 0.f : MASKC, a0.y ? 0.f : MASKC,
                     a0.z ? 0.f : MASKC, a0.w ? 0.f : MASKC};
        float4 f1 = {a1.x ? 0.f : MASKC, a1.y ? 0.f : MASKC,
                     a1.z ? 0.f : MASKC, a1.w ? 0.f : MASKC};
        *(float4*)&Msk[tid * 8]     = f0;
        *(float4*)&Msk[tid * 8 + 4] = f1;
    }

    // Q B-frags, loaded once: B[k = ds*32+quad*8+j][q = qm*16+t16]
    bf16x8 qf[2][2];
    #pragma unroll
    for (int qm = 0; qm < 2; qm++)
        #pragma unroll
        for (int ds = 0; ds < 2; ds++)
            qf[qm][ds] = *(const bf16x8*)&qp[
                (long)(b * SEQ + qt0 + w * 32 + qm * 16 + t16) * CH
                + h * HD + ds * 32 + quad * 8];

    f32x4 oa[4][2];                  // [dt][qm]: out^T [d=16dt+4quad+reg][q]
    float l_r[2];
    #pragma unroll
    for (int dt = 0; dt < 4; dt++)
        #pragma unroll
        for (int qm = 0; qm < 2; qm++)
            oa[dt][qm] = (f32x4){0.f, 0.f, 0.f, 0.f};
    l_r[0] = l_r[1] = 0.f;

    const int srow  = tid >> 2;           // 0..63
    const int scol  = (tid & 3) * 16;     // 0,16,32,48
    const long kbase = (long)(b * SEQ) * CH + h * HD;
    const long vbase = ((long)(b * NH + h) * HD) * SEQ;
    const int NIT = SEQ / 64;

    bf16x8 kr[2];
    // K tile 0 -> regs -> buf0; tile 1 -> regs
    #pragma unroll
    for (int c = 0; c < 2; c++)
        kr[c] = *(const bf16x8*)&kp[kbase + (long)srow * CH + scol + 8 * c];
    #pragma unroll
    for (int c = 0; c < 2; c++)
        *(bf16x8*)&Kt[0][srow * 72 + scol + 8 * c] = kr[c];
    #pragma unroll
    for (int c = 0; c < 2; c++)
        kr[c] = *(const bf16x8*)&kp[kbase + (long)(64 + srow) * CH + scol + 8 * c];
    __syncthreads();

    for (int it = 0; it < NIT; it++) {
        const int buf = it & 1;
        const int kt0 = it * 64;

        // ---- V frags for THIS iter, direct from global (L1/L2-resident).
        // Issued first; consumed after staging+mask+QK+softmax (~400 cy).
        // va[dt][jt] = A[m=d dt*16+t16][k=key jt*16+quad*4]
        bf16x4 va[4][4];
        #pragma unroll
        for (int dt = 0; dt < 4; dt++)
            #pragma unroll
            for (int jt = 0; jt < 4; jt++)
                va[dt][jt] = *(const bf16x4*)&vt[
                    vbase + (long)(dt * 16 + t16) * SEQ + kt0 + jt * 16 + quad * 4];

        // ---- K staging: write it+1's tile, prefetch it+2's ----
        if (it + 1 < NIT) {
            #pragma unroll
            for (int c = 0; c < 2; c++)
                *(bf16x8*)&Kt[buf ^ 1][srow * 72 + scol + 8 * c] = kr[c];
            if (it + 2 < NIT) {
                #pragma unroll
                for (int c = 0; c < 2; c++)
                    kr[c] = *(const bf16x8*)&kp[
                        kbase + (long)(kt0 + 128 + srow) * CH + scol + 8 * c];
            }
        }

        // mask addend (LDS broadcast b128)
        float4 mv4[4];
        #pragma unroll
        for (int jt = 0; jt < 4; jt++)
            mv4[jt] = *(const float4*)&Msk[kt0 + jt * 16 + quad * 4];

        // ---- S^T = K * Q^T  (mask pre-loaded into the accumulator) ----
        f32x4 sa[2][4];
        #pragma unroll
        for (int qm = 0; qm < 2; qm++)
            #pragma unroll
            for (int jt = 0; jt < 4; jt++)
                sa[qm][jt] = (f32x4){mv4[jt].x, mv4[jt].y, mv4[jt].z, mv4[jt].w};
        #pragma unroll
        for (int ds = 0; ds < 2; ds++) {
            bf16x8 kb[4];   // A[m=key t16][k=d]
            #pragma unroll
            for (int jt = 0; jt < 4; jt++)
                kb[jt] = *(bf16x8*)&Kt[buf][(jt * 16 + t16) * 72 + ds * 32 + quad * 8];
            __builtin_amdgcn_s_setprio(1);
            #pragma unroll
            for (int qm = 0; qm < 2; qm++)
                #pragma unroll
                for (int jt = 0; jt < 4; jt++)
                    sa[qm][jt] = __builtin_amdgcn_mfma_f32_16x16x32_bf16(
                        kb[jt], qf[qm][ds], sa[qm][jt], 0, 0, 0);
            __builtin_amdgcn_s_setprio(0);
        }

        // ---- per-jt: softmax slice + PV MFMA (pb live range = 1 jt) ----
        #pragma unroll
        for (int jt = 0; jt < 4; jt++) {
            bf16x4 pbq[2];
            #pragma unroll
            for (int qm = 0; qm < 2; qm++) {
                float p0 = exp2_hw(sa[qm][jt][0]);
                float p1 = exp2_hw(sa[qm][jt][1]);
                float p2 = exp2_hw(sa[qm][jt][2]);
                float p3 = exp2_hw(sa[qm][jt][3]);
                l_r[qm] += (p0 + p1) + (p2 + p3);
                pbq[qm] = pack4_rne(p0, p1, p2, p3);
            }
            __builtin_amdgcn_s_setprio(1);
            #pragma unroll
            for (int dt = 0; dt < 4; dt++)
                #pragma unroll
                for (int qm = 0; qm < 2; qm++)
                    oa[dt][qm] = mfma16x16x16(va[dt][jt], pbq[qm], oa[dt][qm]);
            __builtin_amdgcn_s_setprio(0);
        }
        __syncthreads();
    }

    // ---- epilogue: quad-reduce l, normalize, store out^T -> out ----
    #pragma unroll
    for (int qm = 0; qm < 2; qm++) {
        float l = l_r[qm];
        l += __shfl_xor(l, 16, 64);
        l += __shfl_xor(l, 32, 64);
        float inv = 1.0f / l;
        int q = qt0 + w * 32 + qm * 16 + t16;
        #pragma unroll
        for (int dt = 0; dt < 4; dt++) {
            f32x4 o = oa[dt][qm];
            float4 st = {o[0] * inv, o[1] * inv, o[2] * inv, o[3] * inv};
            *(float4*)&out[((long)(b * SEQ + q) * NH + h) * HD + dt * 16 + quad * 4] = st;
        }
    }
}

extern "C" void kernel_launch(void* const* d_in, const int* in_sizes, int n_in,
                              void* d_out, int out_size, void* d_ws, size_t ws_size,
                              hipStream_t stream) {
    const float* query = (const float*)d_in[0];
    const float* key   = (const float*)d_in[1];
    const int*   amask = (const int*)d_in[2];
    const float* Wq    = (const float*)d_in[3];
    const float* bq    = (const float*)d_in[4];
    const float* Wk    = (const float*)d_in[5];
    const float* bk    = (const float*)d_in[6];
    float* out = (float*)d_out;

    char* ws = (char*)d_ws;
    const long MB = 1024 * 1024;
    short* qc  = (short*)(ws + 0 * MB);    // query bf16 [4096][1024] (8 MB)
    short* kc  = (short*)(ws + 8 * MB);    // key   bf16 [4096][1024] (8 MB)
    short* qp  = (short*)(ws + 16 * MB);   // Q proj bf16 (8 MB)
    short* kp  = (short*)(ws + 24 * MB);   // K proj bf16 (8 MB)
    short* vtr = (short*)(ws + 32 * MB);   // V^T bf16 [B*H][64][2048] (8 MB)
    short* wtq = (short*)(ws + 40 * MB);   // Wq^T bf16 (2 MB)
    short* wtk = (short*)(ws + 42 * MB);   // Wk^T bf16 (2 MB)

    prep<<<dim3(5632), 256, 0, stream>>>(query, key, Wq, Wk, qc, kc, wtq, wtk, vtr);

    proj_mfma<<<dim3(512), 256, 0, stream>>>(qc, kc, wtq, wtk, bq, bk, qp, kp);

    attn_mfma<<<dim3(512), 256, 0, stream>>>(qp, kp, vtr, amask, out);
}

// Round 8
// 172.195 us; speedup vs baseline: 1.6963x; 1.4348x over previous
//
#include <hip/hip_runtime.h>

#define BSZ 2
#define SEQ 2048
#define CH  1024
#define NH  16
#define HD  64
#define LOG2E 1.4426950408889634f
#define MASKC (-14426.950408889634f)   /* -10000 * log2(e) */

typedef short  bf16x8 __attribute__((ext_vector_type(8)));
typedef short  bf16x4 __attribute__((ext_vector_type(4)));
typedef float  f32x4  __attribute__((ext_vector_type(4)));

__device__ __forceinline__ short f2bf(float f) {
    union { float f; unsigned u; } v; v.f = f;
    unsigned r = v.u + 0x7FFFu + ((v.u >> 16) & 1u);   // RNE
    return (short)(r >> 16);
}
// round-half-up bf16 (1 ulp tie-only difference vs RNE, 2 VALU ops)
__device__ __forceinline__ short f2bf_fast(float f) {
    union { float f; unsigned u; } v; v.f = f;
    return (short)((v.u + 0x8000u) >> 16);
}
// Single-instruction exp2 THROUGH THE COMPILER (TRANS-op result hazard needs
// a compiler-inserted wait state; bare inline asm broke correctness earlier).
__device__ __forceinline__ float exp2_hw(float x) {
#if __has_builtin(__builtin_amdgcn_exp2f)
    return __builtin_amdgcn_exp2f(x);
#else
    float r;
    asm volatile("v_exp_f32 %0, %1\n\ts_nop 1" : "=v"(r) : "v"(x));
    return r;
#endif
}

// 16x16x16 bf16 MFMA (K=16): C/D layout of a 16x16 MFMA equals this op's
// B-operand layout, which is what makes register-resident P^T possible.
#if __has_builtin(__builtin_amdgcn_mfma_f32_16x16x16bf16_1k)
__device__ __forceinline__ f32x4 mfma16x16x16(bf16x4 a, bf16x4 b, f32x4 c) {
    return __builtin_amdgcn_mfma_f32_16x16x16bf16_1k(a, b, c, 0, 0, 0);
}
#else
__device__ __forceinline__ f32x4 mfma16x16x16(bf16x4 a, bf16x4 b, f32x4 c) {
    f32x4 d;
    asm("v_mfma_f32_16x16x16_bf16 %0, %1, %2, %3"
        : "=v"(d) : "v"(a), "v"(b), "v"(c));
    return d;
}
#endif

// ---------------------------------------------------------------------------
// PREP mega-kernel: one launch replaces 5 (cast Q, cast K, Wq^T, Wk^T, V^T).
//   blocks [0, 2048)        : query fp32 -> qc bf16
//   blocks [2048, 4096)     : key   fp32 -> kc bf16
//   blocks [4096, 4352)     : Wq [k][n] -> wtq [n][k] bf16
//   blocks [4352, 4608)     : Wk [k][n] -> wtk [n][k] bf16
//   blocks [4608, 5632)     : key [b][s][h*64+d] -> vtr [b*h][d][s] bf16
// ---------------------------------------------------------------------------
__global__ __launch_bounds__(256) void prep(
    const float* __restrict__ query, const float* __restrict__ key,
    const float* __restrict__ Wq, const float* __restrict__ Wk,
    short* __restrict__ qc, short* __restrict__ kc,
    short* __restrict__ wtq, short* __restrict__ wtk,
    short* __restrict__ vtr)
{
    __shared__ float tile[64][65];
    const int bid = blockIdx.x;
    const int tid = threadIdx.x;

    if (bid < 4096) {
        // ---- straight cast, 2048 elements per block ----
        const float* s = (bid < 2048) ? query : key;
        short*       d = (bid < 2048) ? qc : kc;
        long i = ((long)(bid & 2047) * 256 + tid) * 8;
        float4 v0 = *(const float4*)&s[i];
        float4 v1 = *(const float4*)&s[i + 4];
        bf16x8 o;
        o[0] = f2bf(v0.x); o[1] = f2bf(v0.y); o[2] = f2bf(v0.z); o[3] = f2bf(v0.w);
        o[4] = f2bf(v1.x); o[5] = f2bf(v1.y); o[6] = f2bf(v1.z); o[7] = f2bf(v1.w);
        *(bf16x8*)&d[i] = o;
        return;
    }

    // ---- 64x64 tiled transpose + cast ----
    const float* s; short* d;
    int r0, c0, srs, drs;
    if (bid < 4608) {
        int t = bid - 4096;           // 0..511
        s   = (t < 256) ? Wq : Wk;
        d   = (t < 256) ? wtq : wtk;
        t  &= 255;
        r0  = (t >> 4) * 64;          // k
        c0  = (t & 15) * 64;          // n
        srs = CH; drs = CH;
    } else {
        int t = bid - 4608;           // 0..1023
        int z = t >> 5;               // b*16+h, 0..31
        int sy = t & 31;              // s tile, 0..31
        s   = key + (long)(z >> 4) * SEQ * CH + (long)(z & 15) * HD;
        d   = vtr + (long)z * HD * SEQ;
        r0  = sy * 64;                // s
        c0  = 0;                      // d
        srs = CH; drs = SEQ;
    }

    const int r  = tid >> 2;          // 0..63
    const int c4 = (tid & 3) << 4;    // 0,16,32,48
    #pragma unroll
    for (int i = 0; i < 16; i += 4) {
        float4 v = *(const float4*)&s[(long)(r0 + r) * srs + c0 + c4 + i];
        tile[r][c4 + i + 0] = v.x;
        tile[r][c4 + i + 1] = v.y;
        tile[r][c4 + i + 2] = v.z;
        tile[r][c4 + i + 3] = v.w;
    }
    __syncthreads();
    bf16x8 o0, o1;
    #pragma unroll
    for (int i = 0; i < 8; i++) o0[i] = f2bf(tile[c4 + i][r]);
    #pragma unroll
    for (int i = 0; i < 8; i++) o1[i] = f2bf(tile[c4 + 8 + i][r]);
    *(bf16x8*)&d[(long)(c0 + r) * drs + r0 + c4 + 0] = o0;
    *(bf16x8*)&d[(long)(c0 + r) * drs + r0 + c4 + 8] = o1;
}

// ---------------------------------------------------------------------------
// Fused Q+K projection GEMM, all-bf16 inputs.  1D grid, XCD-SWIZZLED (R4):
// blocks sharing an A-panel (same m-tile, 8 n-tiles) land on ONE XCD so the
// 256 KB panel is fetched into that XCD's L2 once.
// Y = bf16((X * W + bias) * scale).  128x128 tile, BK=64 (16 iters), 4 waves
// of 4x4 16x16x32 MFMAs x 2 k-halves.  Double-buffered LDS, ONE barrier per
// iter; staging writes + global prefetch issue before compute.
// ---------------------------------------------------------------------------
__global__ __launch_bounds__(256, 2) void proj_mfma(
    const short* __restrict__ Xq, const short* __restrict__ Xk,
    const short* __restrict__ Wtq, const short* __restrict__ Wtk,
    const float* __restrict__ bq_, const float* __restrict__ bk_,
    short* __restrict__ Yq, short* __restrict__ Yk)
{
    __shared__ short At[2][128 * 72];
    __shared__ short Bt[2][128 * 72];

    // XCD swizzle: bid -> (pair = m,z group on fixed XCD; xtile = n-tile)
    const int bid  = blockIdx.x;           // 0..511
    const int g    = bid >> 3, xcd = bid & 7;
    const int pair = ((g >> 3) << 3) | xcd;   // 0..63 = y*2+z
    const int xt   = g & 7;                   // n-tile 0..7
    const int yy   = pair >> 1;               // m-tile 0..31
    const int zz   = pair & 1;                // operand set

    const short* X    = zz ? Xk  : Xq;
    const short* Wt   = zz ? Wtk : Wtq;
    const float* bias = zz ? bk_ : bq_;
    short*       Y    = zz ? Yk  : Yq;
    const float scale = zz ? 1.0f : (0.125f * LOG2E);  // fold 1/sqrt(D)*log2e into Q

    const int tid  = threadIdx.x;
    const int lane = tid & 63, w = tid >> 6;
    const int quad = lane >> 4, t16 = lane & 15;
    const int m0 = yy * 128, n0 = xt * 128;
    const int srow = tid >> 1;            // 0..127 staging row
    const int shalf = (tid & 1) * 32;     // 0 / 32 k-half (shorts)

    f32x4 acc[4][4];
    #pragma unroll
    for (int i = 0; i < 4; i++)
        #pragma unroll
        for (int j = 0; j < 4; j++)
            acc[i][j] = (f32x4){0.f, 0.f, 0.f, 0.f};

    const int M0 = (w >> 1) * 64, N0 = (w & 1) * 64;
    const int NIT = CH / 64;

    bf16x8 ar[4], br[4];
    // tile 0 -> regs -> buf0; tile 1 -> regs
    #pragma unroll
    for (int c = 0; c < 4; c++) {
        ar[c] = *(const bf16x8*)&X [(long)(m0 + srow) * CH + shalf + 8 * c];
        br[c] = *(const bf16x8*)&Wt[(long)(n0 + srow) * CH + shalf + 8 * c];
    }
    #pragma unroll
    for (int c = 0; c < 4; c++) {
        *(bf16x8*)&At[0][srow * 72 + shalf + 8 * c] = ar[c];
        *(bf16x8*)&Bt[0][srow * 72 + shalf + 8 * c] = br[c];
    }
    #pragma unroll
    for (int c = 0; c < 4; c++) {
        ar[c] = *(const bf16x8*)&X [(long)(m0 + srow) * CH + 64 + shalf + 8 * c];
        br[c] = *(const bf16x8*)&Wt[(long)(n0 + srow) * CH + 64 + shalf + 8 * c];
    }
    __syncthreads();

    for (int it = 0; it < NIT; it++) {
        const int buf = it & 1;
        if (it + 1 < NIT) {
            #pragma unroll
            for (int c = 0; c < 4; c++) {
                *(bf16x8*)&At[buf ^ 1][srow * 72 + shalf + 8 * c] = ar[c];
                *(bf16x8*)&Bt[buf ^ 1][srow * 72 + shalf + 8 * c] = br[c];
            }
            if (it + 2 < NIT) {
                const long ko = (long)(it + 2) * 64;
                #pragma unroll
                for (int c = 0; c < 4; c++) {
                    ar[c] = *(const bf16x8*)&X [(long)(m0 + srow) * CH + ko + shalf + 8 * c];
                    br[c] = *(const bf16x8*)&Wt[(long)(n0 + srow) * CH + ko + shalf + 8 * c];
                }
            }
        }

        #pragma unroll
        for (int kk = 0; kk < 2; kk++) {
            bf16x8 af[4], bw[4];
            #pragma unroll
            for (int im = 0; im < 4; im++)
                af[im] = *(bf16x8*)&At[buf][(M0 + 16 * im + t16) * 72 + kk * 32 + quad * 8];
            #pragma unroll
            for (int jn = 0; jn < 4; jn++)
                bw[jn] = *(bf16x8*)&Bt[buf][(N0 + 16 * jn + t16) * 72 + kk * 32 + quad * 8];
            #pragma unroll
            for (int im = 0; im < 4; im++)
                #pragma unroll
                for (int jn = 0; jn < 4; jn++)
                    acc[im][jn] = __builtin_amdgcn_mfma_f32_16x16x32_bf16(
                        af[im], bw[jn], acc[im][jn], 0, 0, 0);
        }
        __syncthreads();
    }

    #pragma unroll
    for (int jn = 0; jn < 4; jn++) {
        float bs = bias[n0 + N0 + 16 * jn + t16];
        #pragma unroll
        for (int im = 0; im < 4; im++)
            #pragma unroll
            for (int reg = 0; reg < 4; reg++) {
                float y = (acc[im][jn][reg] + bs) * scale;
                Y[(long)(m0 + M0 + 16 * im + 4 * quad + reg) * (NH * HD)
                  + n0 + N0 + 16 * jn + t16] = f2bf(y);
            }
    }
}

// ---------------------------------------------------------------------------
// Flash attention, TRANSPOSED-SCORE form, register-resident P.
// R8 = R5 verified structure (62 µs attn) with KBLK=128: stage 128 keys per
// phase (two sequential 64-key sub-tiles reuse sa), ONE barrier per 128 keys
// (16 barriers instead of 32).
//   R6/R7 lesson (confirmed twice): direct-global fragment loads get SUNK by
//   the register allocator -> serialized load-use stalls.  LDS staging +
//   barrier is the decoupling that works; do not remove it.
//   R5 counters: MfmaUtil 33% + VALU 35% + LDS ~27% ~= sum = measured time
//   (phase-locked pipes).  KBLK=128 halves the per-iter fixed costs (barrier
//   drain s_waitcnt vmcnt(0) lgkmcnt(0) + staging addressing + loop ctrl).
//   LDS: Kt 2x[128][72] + Vt 2x[64][136] + Msk = ~78 KB -> 2 blocks/CU.
//   Staging kr[4]/vr[4] -> ~85 VGPR, safely under the 128 cap.
//   XCD swizzle, LDS mask, per-jt fused softmax+PV, setprio: unchanged.
// ---------------------------------------------------------------------------
__global__ __launch_bounds__(256, 2) void attn_mfma(
    const short* __restrict__ qp,    // [B*S][1024] bf16, pre-scaled 0.125*log2e
    const short* __restrict__ kp,    // [B*S][1024] bf16
    const short* __restrict__ vt,    // [B*H][64][S] bf16 (V transposed)
    const int*   __restrict__ amask, // [B][S] 0/1
    float* __restrict__ out)         // [B][S][H][D] fp32
{
    __shared__ short Kt[2][128 * 72];   // [key][d]   (36 KB)
    __shared__ short Vt[2][64 * 136];   // [d][key]   (34 KB)
    __shared__ float Msk[SEQ];          // mask addend (8 KB)

    // XCD swizzle: bid -> (hb on fixed XCD, q-tile)
    const int bid = blockIdx.x;            // 0..511
    const int g   = bid >> 3, xcd = bid & 7;
    const int hb  = ((g >> 4) << 3) | xcd; // 0..31 = b*16+h, fixed XCD per hb
    const int qt  = g & 15;                // q-tile 0..15

    const int qt0 = qt * 128;
    const int h   = hb & 15;
    const int b   = hb >> 4;
    const int tid = threadIdx.x;
    const int lane = tid & 63, w = tid >> 6;
    const int quad = lane >> 4, t16 = lane & 15;

    // ---- mask row -> LDS float addend, once ----
    {
        int4 a0 = *(const int4*)&amask[b * SEQ + tid * 8];
        int4 a1 = *(const int4*)&amask[b * SEQ + tid * 8 + 4];
        float4 f0 = {a0.x ? 0.f : MASKC, a0.y ? 0.f : MASKC,
                     a0.z ? 0.f : MASKC, a0.w ? 0.f : MASKC};
        float4 f1 = {a1.x ? 0.f : MASKC, a1.y ? 0.f : MASKC,
                     a1.z ? 0.f : MASKC, a1.w ? 0.f : MASKC};
        *(float4*)&Msk[tid * 8]     = f0;
        *(float4*)&Msk[tid * 8 + 4] = f1;
    }

    // Q B-frags, loaded once: B[k = ds*32+quad*8+j][q = qm*16+t16]
    bf16x8 qf[2][2];
    #pragma unroll
    for (int qm = 0; qm < 2; qm++)
        #pragma unroll
        for (int ds = 0; ds < 2; ds++)
            qf[qm][ds] = *(const bf16x8*)&qp[
                (long)(b * SEQ + qt0 + w * 32 + qm * 16 + t16) * CH
                + h * HD + ds * 32 + quad * 8];

    f32x4 oa[4][2];                  // [dt][qm]: out^T [d=16dt+4quad+reg][q]
    float l_r[2];
    #pragma unroll
    for (int dt = 0; dt < 4; dt++)
        #pragma unroll
        for (int qm = 0; qm < 2; qm++)
            oa[dt][qm] = (f32x4){0.f, 0.f, 0.f, 0.f};
    l_r[0] = l_r[1] = 0.f;

    // K staging map: 128 rows x 128 B; thread -> row tid>>1, 64 B half
    const int ksrow = tid >> 1;           // 0..127
    const int kscol = (tid & 1) * 32;     // 0 / 32 (shorts)
    // V staging map: 64 rows x 256 B; thread -> row tid>>2, 64 B quarter
    const int vsrow = tid >> 2;           // 0..63
    const int vscol = (tid & 3) * 32;     // 0,32,64,96 (shorts)
    const long kbase = (long)(b * SEQ) * CH + h * HD;
    const long vbase = ((long)(b * NH + h) * HD) * SEQ;
    const int NIT = SEQ / 128;            // 16 phases

    bf16x8 kr[4], vr[4];
    // phase 0 -> regs -> buf0; phase 1 -> regs
    #pragma unroll
    for (int c = 0; c < 4; c++) {
        kr[c] = *(const bf16x8*)&kp[kbase + (long)ksrow * CH + kscol + 8 * c];
        vr[c] = *(const bf16x8*)&vt[vbase + (long)vsrow * SEQ + vscol + 8 * c];
    }
    #pragma unroll
    for (int c = 0; c < 4; c++) {
        *(bf16x8*)&Kt[0][ksrow * 72 + kscol + 8 * c] = kr[c];
        *(bf16x8*)&Vt[0][vsrow * 136 + vscol + 8 * c] = vr[c];
    }
    #pragma unroll
    for (int c = 0; c < 4; c++) {
        kr[c] = *(const bf16x8*)&kp[kbase + (long)(128 + ksrow) * CH + kscol + 8 * c];
        vr[c] = *(const bf16x8*)&vt[vbase + (long)vsrow * SEQ + 128 + vscol + 8 * c];
    }
    __syncthreads();

    for (int it = 0; it < NIT; it++) {
        const int buf = it & 1;
        const int kt0 = it * 128;

        // ---- staging: write it+1's phase, prefetch it+2's ----
        if (it + 1 < NIT) {
            #pragma unroll
            for (int c = 0; c < 4; c++) {
                *(bf16x8*)&Kt[buf ^ 1][ksrow * 72 + kscol + 8 * c] = kr[c];
                *(bf16x8*)&Vt[buf ^ 1][vsrow * 136 + vscol + 8 * c] = vr[c];
            }
            if (it + 2 < NIT) {
                const int kn = kt0 + 256;
                #pragma unroll
                for (int c = 0; c < 4; c++) {
                    kr[c] = *(const bf16x8*)&kp[kbase + (long)(kn + ksrow) * CH + kscol + 8 * c];
                    vr[c] = *(const bf16x8*)&vt[vbase + (long)vsrow * SEQ + kn + vscol + 8 * c];
                }
            }
        }

        // ---- two 64-key sub-tiles, sa reused (no extra VGPR) ----
        #pragma unroll
        for (int sub = 0; sub < 2; sub++) {
            const int ko = sub * 64;     // key offset within phase

            // mask addend (LDS broadcast b128)
            float4 mv4[4];
            #pragma unroll
            for (int jt = 0; jt < 4; jt++)
                mv4[jt] = *(const float4*)&Msk[kt0 + ko + jt * 16 + quad * 4];

            // ---- S^T = K * Q^T  (mask pre-loaded into the accumulator) ----
            f32x4 sa[2][4];
            #pragma unroll
            for (int qm = 0; qm < 2; qm++)
                #pragma unroll
                for (int jt = 0; jt < 4; jt++)
                    sa[qm][jt] = (f32x4){mv4[jt].x, mv4[jt].y, mv4[jt].z, mv4[jt].w};
            #pragma unroll
            for (int ds = 0; ds < 2; ds++) {
                bf16x8 kb[4];   // A[m=key t16][k=d]
                #pragma unroll
                for (int jt = 0; jt < 4; jt++)
                    kb[jt] = *(bf16x8*)&Kt[buf][(ko + jt * 16 + t16) * 72 + ds * 32 + quad * 8];
                __builtin_amdgcn_s_setprio(1);
                #pragma unroll
                for (int qm = 0; qm < 2; qm++)
                    #pragma unroll
                    for (int jt = 0; jt < 4; jt++)
                        sa[qm][jt] = __builtin_amdgcn_mfma_f32_16x16x32_bf16(
                            kb[jt], qf[qm][ds], sa[qm][jt], 0, 0, 0);
                __builtin_amdgcn_s_setprio(0);
            }

            // ---- per-jt: softmax slice + PV MFMA (pb live range = 1 jt) ----
            #pragma unroll
            for (int jt = 0; jt < 4; jt++) {
                bf16x4 pbq[2];
                #pragma unroll
                for (int qm = 0; qm < 2; qm++) {
                    float p0 = exp2_hw(sa[qm][jt][0]);
                    float p1 = exp2_hw(sa[qm][jt][1]);
                    float p2 = exp2_hw(sa[qm][jt][2]);
                    float p3 = exp2_hw(sa[qm][jt][3]);
                    l_r[qm] += (p0 + p1) + (p2 + p3);
                    bf16x4 pk;
                    pk[0] = f2bf_fast(p0); pk[1] = f2bf_fast(p1);
                    pk[2] = f2bf_fast(p2); pk[3] = f2bf_fast(p3);
                    pbq[qm] = pk;
                }
                bf16x4 va[4];   // A[m=d t16][k=key 4quad+j]
                #pragma unroll
                for (int dt = 0; dt < 4; dt++)
                    va[dt] = *(bf16x4*)&Vt[buf][(dt * 16 + t16) * 136 + ko + jt * 16 + quad * 4];
                __builtin_amdgcn_s_setprio(1);
                #pragma unroll
                for (int dt = 0; dt < 4; dt++)
                    #pragma unroll
                    for (int qm = 0; qm < 2; qm++)
                        oa[dt][qm] = mfma16x16x16(va[dt], pbq[qm], oa[dt][qm]);
                __builtin_amdgcn_s_setprio(0);
            }
        }
        __syncthreads();
    }

    // ---- epilogue: quad-reduce l, normalize, store out^T -> out ----
    #pragma unroll
    for (int qm = 0; qm < 2; qm++) {
        float l = l_r[qm];
        l += __shfl_xor(l, 16, 64);
        l += __shfl_xor(l, 32, 64);
        float inv = 1.0f / l;
        int q = qt0 + w * 32 + qm * 16 + t16;
        #pragma unroll
        for (int dt = 0; dt < 4; dt++) {
            f32x4 o = oa[dt][qm];
            float4 st = {o[0] * inv, o[1] * inv, o[2] * inv, o[3] * inv};
            *(float4*)&out[((long)(b * SEQ + q) * NH + h) * HD + dt * 16 + quad * 4] = st;
        }
    }
}

extern "C" void kernel_launch(void* const* d_in, const int* in_sizes, int n_in,
                              void* d_out, int out_size, void* d_ws, size_t ws_size,
                              hipStream_t stream) {
    const float* query = (const float*)d_in[0];
    const float* key   = (const float*)d_in[1];
    const int*   amask = (const int*)d_in[2];
    const float* Wq    = (const float*)d_in[3];
    const float* bq    = (const float*)d_in[4];
    const float* Wk    = (const float*)d_in[5];
    const float* bk    = (const float*)d_in[6];
    float* out = (float*)d_out;

    char* ws = (char*)d_ws;
    const long MB = 1024 * 1024;
    short* qc  = (short*)(ws + 0 * MB);    // query bf16 [4096][1024] (8 MB)
    short* kc  = (short*)(ws + 8 * MB);    // key   bf16 [4096][1024] (8 MB)
    short* qp  = (short*)(ws + 16 * MB);   // Q proj bf16 (8 MB)
    short* kp  = (short*)(ws + 24 * MB);   // K proj bf16 (8 MB)
    short* vtr = (short*)(ws + 32 * MB);   // V^T bf16 [B*H][64][2048] (8 MB)
    short* wtq = (short*)(ws + 40 * MB);   // Wq^T bf16 (2 MB)
    short* wtk = (short*)(ws + 42 * MB);   // Wk^T bf16 (2 MB)

    prep<<<dim3(5632), 256, 0, stream>>>(query, key, Wq, Wk, qc, kc, wtq, wtk, vtr);

    proj_mfma<<<dim3(512), 256, 0, stream>>>(qc, kc, wtq, wtk, bq, bk, qp, kp);

    attn_mfma<<<dim3(512), 256, 0, stream>>>(qp, kp, vtr, amask, out);
}